// Round 2
// baseline (290.433 us; speedup 1.0000x reference)
//
#include <hip/hip_runtime.h>
#include <hip/hip_bf16.h>
#include <math.h>

typedef __hip_bfloat16 bf16;
typedef __attribute__((ext_vector_type(8))) short short8;
typedef __attribute__((ext_vector_type(4))) short short4v;
typedef __attribute__((ext_vector_type(4))) float floatx4;

#define MFMA16(a, b, c) __builtin_amdgcn_mfma_f32_16x16x32_bf16((a), (b), (c), 0, 0, 0)

typedef const __attribute__((address_space(1))) void* as1_cvp;
typedef __attribute__((address_space(3))) void* as3_vp;

__device__ __forceinline__ void gload_lds16(const bf16* g, bf16* lds_uni) {
    __builtin_amdgcn_global_load_lds((as1_cvp)g, (as3_vp)lds_uni, 16, 0, 0);
}

// ---------------------------------------------------------------------------
// Single-launch fp32 -> bf16 convert of all 5 inputs (segmented grid).
// ---------------------------------------------------------------------------
__global__ __launch_bounds__(256) void cvt_all(
    const float* __restrict__ a0, const float* __restrict__ a1,
    const float* __restrict__ a2, const float* __restrict__ a3,
    const float* __restrict__ a4,
    bf16* __restrict__ d0, bf16* __restrict__ d1, bf16* __restrict__ d2,
    bf16* __restrict__ d3, bf16* __restrict__ d4)
{
    const int b = blockIdx.x;
    const float* src; bf16* dst; int off;
    if (b < 2048)      { src = a0; dst = d0; off = b; }
    else if (b < 4096) { src = a1; dst = d1; off = b - 2048; }
    else if (b < 4608) { src = a2; dst = d2; off = b - 4096; }
    else if (b < 5120) { src = a3; dst = d3; off = b - 4608; }
    else               { src = a4; dst = d4; off = b - 5120; }
    const int i = (off * 256 + threadIdx.x) * 8;
    const float4 x = *(const float4*)(src + i);
    const float4 y = *(const float4*)(src + i + 4);
    bf16 t[8];
    t[0] = __float2bfloat16(x.x); t[1] = __float2bfloat16(x.y);
    t[2] = __float2bfloat16(x.z); t[3] = __float2bfloat16(x.w);
    t[4] = __float2bfloat16(y.x); t[5] = __float2bfloat16(y.y);
    t[6] = __float2bfloat16(y.z); t[7] = __float2bfloat16(y.w);
    *(short8*)(dst + i) = *(const short8*)t;
}

// ---------------------------------------------------------------------------
// 128x64-tile GEMM K-loop (BK=64 as two 32-slices per barrier pair).
// ---------------------------------------------------------------------------
#define GEMM_K_LOOP_12864(KB)                                                   \
    for (int k0 = 0; k0 < (KB); k0 += 64) {                                     \
        gload_lds16(gA + k0,            ldsA);                                  \
        gload_lds16(gA + A64 + k0,      ldsA + 2048);                           \
        gload_lds16(gB + k0,            ldsB);                                  \
        gload_lds16(gA + k0 + 32,       ldsA + 4096);                           \
        gload_lds16(gA + A64 + k0 + 32, ldsA + 6144);                           \
        gload_lds16(gB + k0 + 32,       ldsB + 2048);                           \
        __syncthreads();                                                        \
        _Pragma("unroll")                                                       \
        for (int hh = 0; hh < 2; ++hh) {                                        \
            short8 af[2], bfr[4];                                               \
            _Pragma("unroll")                                                   \
            for (int i = 0; i < 2; ++i)                                         \
                af[i] = *(const short8*)&As[hh * 4096 + (w * 32 + i * 16 + l15) * 32 + quad * 8]; \
            _Pragma("unroll")                                                   \
            for (int j = 0; j < 4; ++j)                                         \
                bfr[j] = *(const short8*)&Bs[hh * 2048 + (j * 16 + l15) * 32 + quad * 8]; \
            _Pragma("unroll")                                                   \
            for (int i = 0; i < 2; ++i)                                         \
                _Pragma("unroll")                                               \
                for (int j = 0; j < 4; ++j)                                     \
                    acc[i][j] = MFMA16(af[i], bfr[j], acc[i][j]);               \
        }                                                                       \
        __syncthreads();                                                        \
    }

// ---------------------------------------------------------------------------
// Fused QKV projection, 128x64 tiles. grid (48,16):
//   bx  0..31: Q (RoPE + 1/8 scale -> qb)
//   bx 32..39: K (RoPE -> kb)
//   bx 40..47: V (transpose-store -> vt[512][2048])
// ---------------------------------------------------------------------------
__global__ __launch_bounds__(256) void gemm_qkv(
    const bf16* __restrict__ A, const bf16* __restrict__ Wq,
    const bf16* __restrict__ Wk, const bf16* __restrict__ Wv,
    bf16* __restrict__ qb, bf16* __restrict__ kb, bf16* __restrict__ vt)
{
    constexpr int LDK = 2048;
    __shared__ bf16 As[2 * 128 * 32];   // 16 KB
    __shared__ bf16 Bs[2 * 64 * 32];    //  8 KB

    const int tid  = threadIdx.x;
    const int lane = tid & 63;
    const int w    = tid >> 6;
    const int quad = lane >> 4, l15 = lane & 15;
    const int bx = blockIdx.x, by = blockIdx.y;

    const bf16* Bp; int bxl, mode;
    if (bx < 32)      { Bp = Wq; bxl = bx;      mode = 0; }
    else if (bx < 40) { Bp = Wk; bxl = bx - 32; mode = 1; }
    else              { Bp = Wv; bxl = bx - 40; mode = 2; }

    floatx4 acc[2][4];
#pragma unroll
    for (int i = 0; i < 2; ++i)
#pragma unroll
        for (int j = 0; j < 4; ++j) {
            floatx4 z = {0.f, 0.f, 0.f, 0.f};
            acc[i][j] = z;
        }

    const int srow = tid >> 2;          // 0..63
    const int sch  = (tid & 3) * 8;
    const bf16* gA = A  + (size_t)(by * 128 + srow) * LDK + sch;
    const bf16* gB = Bp + (size_t)(bxl * 64 + srow) * LDK + sch;
    const size_t A64 = (size_t)64 * LDK;
    bf16* ldsA = As + w * 512;
    bf16* ldsB = Bs + w * 512;

    GEMM_K_LOOP_12864(LDK)

    // epilogue. C/D layout: col = lane&15, row = quad*4 + reg  [m89/m91]
    if (mode == 2) {
        // V: transpose-store vt[d][s], 4 consecutive s packed -> b64
#pragma unroll
        for (int i = 0; i < 2; ++i)
#pragma unroll
            for (int j = 0; j < 4; ++j) {
                const int col = bxl * 64 + j * 16 + l15;                  // d
                const int rowb = by * 128 + w * 32 + i * 16 + quad * 4;   // s base
                bf16 t[4];
#pragma unroll
                for (int r = 0; r < 4; ++r) t[r] = __float2bfloat16(acc[i][j][r]);
                *(short4v*)&vt[(size_t)col * 2048 + rowb] = *(const short4v*)t;
            }
    } else {
        // Q/K: RoPE (head dim 64; tile is head-aligned, d = j*16+l15,
        // partner j^2 in-wave). Q also pre-scaled by 1/8.
        bf16* C = (mode == 0) ? qb : kb;
        const int Nn = (mode == 0) ? 2048 : 512;
        const float scale = (mode == 0) ? 0.125f : 1.0f;
        const float LOG2_1E4 = 13.28771237954945f;
        const float ifr0 = exp2f(-((float)l15) * (LOG2_1E4 / 32.f));
        const float ifr1 = exp2f(-((float)(16 + l15)) * (LOG2_1E4 / 32.f));
#pragma unroll
        for (int i = 0; i < 2; ++i) {
#pragma unroll
            for (int r = 0; r < 4; ++r) {
                const int row = by * 128 + w * 32 + i * 16 + quad * 4 + r;
                float s0, c0, s1, c1;
                sincosf((float)row * ifr0, &s0, &c0);
                sincosf((float)row * ifr1, &s1, &c1);
#pragma unroll
                for (int j = 0; j < 4; ++j) {
                    const float x  = acc[i][j][r];
                    const float xp = acc[i][j ^ 2][r];
                    const float cs = (j & 1) ? c1 : c0;
                    const float sn = (j & 1) ? s1 : s0;
                    const float oo = (x * cs + ((j < 2) ? -xp : xp) * sn) * scale;
                    const int col = bxl * 64 + j * 16 + l15;
                    C[(size_t)row * Nn + col] = __float2bfloat16(oo);
                }
            }
        }
    }
}

// ---------------------------------------------------------------------------
// O-projection, 128x64 tiles: grid (32,16) = 512 blocks. fp32 store.
// ---------------------------------------------------------------------------
__global__ __launch_bounds__(256) void gemm_out(
    const bf16* __restrict__ A, const bf16* __restrict__ B, float* __restrict__ C)
{
    constexpr int LDK = 2048;
    __shared__ bf16 As[2 * 128 * 32];
    __shared__ bf16 Bs[2 * 64 * 32];

    const int tid  = threadIdx.x;
    const int lane = tid & 63;
    const int w    = tid >> 6;
    const int quad = lane >> 4, l15 = lane & 15;
    const int bx = blockIdx.x, by = blockIdx.y;

    floatx4 acc[2][4];
#pragma unroll
    for (int i = 0; i < 2; ++i)
#pragma unroll
        for (int j = 0; j < 4; ++j) {
            floatx4 z = {0.f, 0.f, 0.f, 0.f};
            acc[i][j] = z;
        }

    const int srow = tid >> 2;
    const int sch  = (tid & 3) * 8;
    const bf16* gA = A + (size_t)(by * 128 + srow) * LDK + sch;
    const bf16* gB = B + (size_t)(bx * 64 + srow) * LDK + sch;
    const size_t A64 = (size_t)64 * LDK;
    bf16* ldsA = As + w * 512;
    bf16* ldsB = Bs + w * 512;

    GEMM_K_LOOP_12864(LDK)

#pragma unroll
    for (int i = 0; i < 2; ++i)
#pragma unroll
        for (int j = 0; j < 4; ++j)
#pragma unroll
            for (int r = 0; r < 4; ++r) {
                const int row = by * 128 + w * 32 + i * 16 + quad * 4 + r;
                const int col = bx * 64 + j * 16 + l15;
                C[(size_t)row * 2048 + col] = acc[i][j][r];
            }
}

// ---------------------------------------------------------------------------
// Causal GQA flash attention v6: BARRIER-FREE, direct-from-L2 K/V.
//
// Round-1 post-mortem: un-pairing broke CU load balance (gridDim.x=32
// divides 256 -> every CU got 4 equal-length blocks; bx=0 CUs got 4x32
// iters). Reverted to the uniform 33-iter diagonal pairing.
//
// Round-0/1 arithmetic: 2365 cyc/block-iter/CU, of which LDS pipe ~1300
// (24 b128-eq/wave: kf 8, vf 8, pf 2, P-writes 2, staging 4) and the
// rest a serial chain with only 2-way block overlap. K (2 MB) and V^T
// (2 MB) are L2-resident -> staging them through LDS is pure overhead
// (m169 lesson). v6: each wave reads K/V fragments DIRECTLY global->reg:
//   - LDS drops to the per-wave P round-trip only (8.7 KB/block)
//   - the K/V double-buffer dies -> NO __syncthreads in the loop at all;
//     waves slip freely (latency hiding without more blocks)
//   - K(kt+1) prefetched into regs mid-iteration; V(kt) issued at
//     iteration top, consumed after S^T+exp (~400 cyc self-hiding)
// Cost: 4 waves re-read the shared 8KB K/V tiles -> 16 KB/wave-iter from
// L2 (~1.06 GB total, ~31 us floor at 34.5 TB/s). Block-id swizzle
// h=id&31 puts 4 kv-heads per XCD (2 MB hot set <= 4 MB L2).
// ---------------------------------------------------------------------------
__global__ __launch_bounds__(256) void fattn6(
    const bf16* __restrict__ q, const bf16* __restrict__ k,
    const bf16* __restrict__ vt, bf16* __restrict__ o)
{
    __shared__ bf16 Ps[4][16 * 68];

    const int id = blockIdx.x;
    const int h = id & 31;              // XCD = id%8 -> 4 kv-heads per XCD
    const int tpair = id >> 5;          // 0..15
    const int kvh = h >> 2;             // GQA groups = 4
    const int tid = threadIdx.x, lane = tid & 63, w = tid >> 6;
    const int quad = lane >> 4, l15 = lane & 15;
    bf16* P = Ps[w];

    short ob[8];
#pragma unroll
    for (int e = 0; e < 8; ++e) ob[e] = (short)0x3F80;  // bf16 1.0
    const short8 ones = *(const short8*)ob;

    // per-lane K/V base pointers (fragment-layout addressing)
    // kf[n][ks] <- k[(kt*64 + n*16 + l15)*512 + kvh*64 + ks*32 + quad*8]
    const bf16* kgl = k  + (size_t)l15 * 512 + kvh * 64 + quad * 8;
    // vf[n4][ks2] <- vt[(kvh*64 + n4*16 + l15)*2048 + kt*64 + ks2*32 + quad*8]
    const bf16* vgl = vt + (size_t)(kvh * 64 + l15) * 2048 + quad * 8;

#pragma unroll 1
    for (int ph = 0; ph < 2; ++ph) {
        const int a = ph ? (31 - tpair) : tpair;
        const int qrow0 = a * 64 + w * 16;

        short8 qf[2];
#pragma unroll
        for (int ks = 0; ks < 2; ++ks)
            qf[ks] = *(const short8*)&q[(size_t)(qrow0 + l15) * 2048 + h * 64 + ks * 32 + quad * 8];

        floatx4 o_acc[4], l_acc;
#pragma unroll
        for (int n4 = 0; n4 < 4; ++n4) {
            floatx4 z = {0.f, 0.f, 0.f, 0.f};
            o_acc[n4] = z;
        }
        { floatx4 z = {0.f, 0.f, 0.f, 0.f}; l_acc = z; }

        // preload K(0) into regs
        short8 kf[4][2];
#pragma unroll
        for (int n = 0; n < 4; ++n)
#pragma unroll
            for (int ks = 0; ks < 2; ++ks)
                kf[n][ks] = *(const short8*)(kgl + (size_t)(n * 16) * 512 + ks * 32);

        for (int kt = 0; kt <= a; ++kt) {
            // V(kt) loads issued at iteration top; consumed after S^T+exp
            short8 vf[4][2];
#pragma unroll
            for (int n4 = 0; n4 < 4; ++n4)
#pragma unroll
                for (int ks2 = 0; ks2 < 2; ++ks2)
                    vf[n4][ks2] = *(const short8*)(vgl + (size_t)(n4 * 16) * 2048
                                                   + kt * 64 + ks2 * 32);

            // S^T = K Q^T: A=kf (m=skey), B=qf (n=qrow).
            // C: col=l15 -> qrow, row=quad*4+r -> skey = n*16+quad*4+r.
            floatx4 s_acc[4];
#pragma unroll
            for (int n = 0; n < 4; ++n) {
                floatx4 z = {0.f, 0.f, 0.f, 0.f};
                s_acc[n] = z;
            }
            __builtin_amdgcn_s_setprio(1);
#pragma unroll
            for (int n = 0; n < 4; ++n)
#pragma unroll
                for (int ks = 0; ks < 2; ++ks)
                    s_acc[n] = MFMA16(kf[n][ks], qf[ks], s_acc[n]);
            __builtin_amdgcn_s_setprio(0);

            // prefetch K(kt+1) into regs (no barrier constraint)
            short8 kn[4][2];
            if (kt < a) {
                const bf16* kgn = kgl + (size_t)((kt + 1) * 64) * 512;
#pragma unroll
                for (int n = 0; n < 4; ++n)
#pragma unroll
                    for (int ks = 0; ks < 2; ++ks)
                        kn[n][ks] = *(const short8*)(kgn + (size_t)(n * 16) * 512 + ks * 32);
            }

            // exp -> P[qrow][skey], 4 consecutive skeys per lane -> b64 write
            if (kt < a) {
#pragma unroll
                for (int n = 0; n < 4; ++n) {
                    bf16 t4[4];
#pragma unroll
                    for (int r = 0; r < 4; ++r)
                        t4[r] = __float2bfloat16(__expf(s_acc[n][r]));
                    *(short4v*)&P[l15 * 68 + n * 16 + quad * 4] = *(const short4v*)t4;
                }
            } else {
                // diagonal: allow skey <= qrow (within 64-row block)
#pragma unroll
                for (int n = 0; n < 4; ++n) {
                    bf16 t4[4];
#pragma unroll
                    for (int r = 0; r < 4; ++r) {
                        const bool okc = (n * 16 + quad * 4 + r) <= (w * 16 + l15);
                        t4[r] = __float2bfloat16(okc ? __expf(s_acc[n][r]) : 0.f);
                    }
                    *(short4v*)&P[l15 * 68 + n * 16 + quad * 4] = *(const short4v*)t4;
                }
            }

            __builtin_amdgcn_s_setprio(1);
#pragma unroll
            for (int ks2 = 0; ks2 < 2; ++ks2) {
                const short8 pf = *(const short8*)&P[l15 * 68 + ks2 * 32 + quad * 8];
                l_acc = MFMA16(pf, ones, l_acc);
#pragma unroll
                for (int n4 = 0; n4 < 4; ++n4)
                    o_acc[n4] = MFMA16(pf, vf[n4][ks2], o_acc[n4]);
            }
            __builtin_amdgcn_s_setprio(0);

            if (kt < a) {
#pragma unroll
                for (int n = 0; n < 4; ++n)
#pragma unroll
                    for (int ks = 0; ks < 2; ++ks)
                        kf[n][ks] = kn[n][ks];
            }
        }

#pragma unroll
        for (int n4 = 0; n4 < 4; ++n4)
#pragma unroll
            for (int r = 0; r < 4; ++r) {
                const float val = o_acc[n4][r] / l_acc[r];
                const int row = qrow0 + quad * 4 + r;
                const int col = h * 64 + n4 * 16 + l15;
                o[(size_t)row * 2048 + col] = __float2bfloat16(val);
            }
    }
}

// ---------------------------------------------------------------------------
extern "C" void kernel_launch(void* const* d_in, const int* in_sizes, int n_in,
                              void* d_out, int out_size, void* d_ws, size_t ws_size,
                              hipStream_t stream)
{
    const float* hs = (const float*)d_in[0];
    const float* Wq = (const float*)d_in[1];
    const float* Wk = (const float*)d_in[2];
    const float* Wv = (const float*)d_in[3];
    const float* Wo = (const float*)d_in[4];
    float* out = (float*)d_out;

    bf16* ws  = (bf16*)d_ws;
    bf16* hsb = ws;                  // 4,194,304
    bf16* Wqb = ws + 4194304;        // 4,194,304
    bf16* Wkb = ws + 8388608;        // 1,048,576
    bf16* Wvb = ws + 9437184;        // 1,048,576
    bf16* Wob = ws + 10485760;       // 4,194,304
    bf16* qb  = ws + 14680064;       // 4,194,304  (RoPE'd, 1/8-scaled)
    bf16* kb  = ws + 18874368;       // 1,048,576  (RoPE'd)
    bf16* vtb = ws + 19922944;       // 1,048,576  (V^T [512][2048])
    bf16* ab  = ws + 20971520;       // 4,194,304  (attention out)

    dim3 blk(256);
    cvt_all<<<7168, blk, 0, stream>>>(hs, Wq, Wk, Wv, Wo, hsb, Wqb, Wkb, Wvb, Wob);
    gemm_qkv<<<dim3(48, 16), blk, 0, stream>>>(hsb, Wqb, Wkb, Wvb, qb, kb, vtb);
    fattn6<<<dim3(512), blk, 0, stream>>>(qb, kb, vtb, ab);
    gemm_out<<<dim3(32, 16), blk, 0, stream>>>(ab, Wob, out);
}

// Round 3
// 240.043 us; speedup vs baseline: 1.2099x; 1.2099x over previous
//
#include <hip/hip_runtime.h>
#include <hip/hip_bf16.h>
#include <math.h>

typedef __hip_bfloat16 bf16;
typedef __attribute__((ext_vector_type(8))) short short8;
typedef __attribute__((ext_vector_type(4))) short short4v;
typedef __attribute__((ext_vector_type(4))) float floatx4;

#define MFMA16(a, b, c) __builtin_amdgcn_mfma_f32_16x16x32_bf16((a), (b), (c), 0, 0, 0)

typedef const __attribute__((address_space(1))) void* as1_cvp;
typedef __attribute__((address_space(3))) void* as3_vp;

__device__ __forceinline__ void gload_lds16(const bf16* g, bf16* lds_uni) {
    __builtin_amdgcn_global_load_lds((as1_cvp)g, (as3_vp)lds_uni, 16, 0, 0);
}

// ---------------------------------------------------------------------------
// Single-launch fp32 -> bf16 convert of all 5 inputs (segmented grid).
// ---------------------------------------------------------------------------
__global__ __launch_bounds__(256) void cvt_all(
    const float* __restrict__ a0, const float* __restrict__ a1,
    const float* __restrict__ a2, const float* __restrict__ a3,
    const float* __restrict__ a4,
    bf16* __restrict__ d0, bf16* __restrict__ d1, bf16* __restrict__ d2,
    bf16* __restrict__ d3, bf16* __restrict__ d4)
{
    const int b = blockIdx.x;
    const float* src; bf16* dst; int off;
    if (b < 2048)      { src = a0; dst = d0; off = b; }
    else if (b < 4096) { src = a1; dst = d1; off = b - 2048; }
    else if (b < 4608) { src = a2; dst = d2; off = b - 4096; }
    else if (b < 5120) { src = a3; dst = d3; off = b - 4608; }
    else               { src = a4; dst = d4; off = b - 5120; }
    const int i = (off * 256 + threadIdx.x) * 8;
    const float4 x = *(const float4*)(src + i);
    const float4 y = *(const float4*)(src + i + 4);
    bf16 t[8];
    t[0] = __float2bfloat16(x.x); t[1] = __float2bfloat16(x.y);
    t[2] = __float2bfloat16(x.z); t[3] = __float2bfloat16(x.w);
    t[4] = __float2bfloat16(y.x); t[5] = __float2bfloat16(y.y);
    t[6] = __float2bfloat16(y.z); t[7] = __float2bfloat16(y.w);
    *(short8*)(dst + i) = *(const short8*)t;
}

// ---------------------------------------------------------------------------
// 128x64-tile GEMM K-loop (BK=64 as two 32-slices per barrier pair).
// ---------------------------------------------------------------------------
#define GEMM_K_LOOP_12864(KB)                                                   \
    for (int k0 = 0; k0 < (KB); k0 += 64) {                                     \
        gload_lds16(gA + k0,            ldsA);                                  \
        gload_lds16(gA + A64 + k0,      ldsA + 2048);                           \
        gload_lds16(gB + k0,            ldsB);                                  \
        gload_lds16(gA + k0 + 32,       ldsA + 4096);                           \
        gload_lds16(gA + A64 + k0 + 32, ldsA + 6144);                           \
        gload_lds16(gB + k0 + 32,       ldsB + 2048);                           \
        __syncthreads();                                                        \
        _Pragma("unroll")                                                       \
        for (int hh = 0; hh < 2; ++hh) {                                        \
            short8 af[2], bfr[4];                                               \
            _Pragma("unroll")                                                   \
            for (int i = 0; i < 2; ++i)                                         \
                af[i] = *(const short8*)&As[hh * 4096 + (w * 32 + i * 16 + l15) * 32 + quad * 8]; \
            _Pragma("unroll")                                                   \
            for (int j = 0; j < 4; ++j)                                         \
                bfr[j] = *(const short8*)&Bs[hh * 2048 + (j * 16 + l15) * 32 + quad * 8]; \
            _Pragma("unroll")                                                   \
            for (int i = 0; i < 2; ++i)                                         \
                _Pragma("unroll")                                               \
                for (int j = 0; j < 4; ++j)                                     \
                    acc[i][j] = MFMA16(af[i], bfr[j], acc[i][j]);               \
        }                                                                       \
        __syncthreads();                                                        \
    }

// ---------------------------------------------------------------------------
// Fused QKV projection, 128x64 tiles. grid (48,16):
//   bx  0..31: Q (RoPE + 1/8 scale -> qb)
//   bx 32..39: K (RoPE -> kb)
//   bx 40..47: V (transpose-store -> vt[512][2048])
// ---------------------------------------------------------------------------
__global__ __launch_bounds__(256) void gemm_qkv(
    const bf16* __restrict__ A, const bf16* __restrict__ Wq,
    const bf16* __restrict__ Wk, const bf16* __restrict__ Wv,
    bf16* __restrict__ qb, bf16* __restrict__ kb, bf16* __restrict__ vt)
{
    constexpr int LDK = 2048;
    __shared__ bf16 As[2 * 128 * 32];   // 16 KB
    __shared__ bf16 Bs[2 * 64 * 32];    //  8 KB

    const int tid  = threadIdx.x;
    const int lane = tid & 63;
    const int w    = tid >> 6;
    const int quad = lane >> 4, l15 = lane & 15;
    const int bx = blockIdx.x, by = blockIdx.y;

    const bf16* Bp; int bxl, mode;
    if (bx < 32)      { Bp = Wq; bxl = bx;      mode = 0; }
    else if (bx < 40) { Bp = Wk; bxl = bx - 32; mode = 1; }
    else              { Bp = Wv; bxl = bx - 40; mode = 2; }

    floatx4 acc[2][4];
#pragma unroll
    for (int i = 0; i < 2; ++i)
#pragma unroll
        for (int j = 0; j < 4; ++j) {
            floatx4 z = {0.f, 0.f, 0.f, 0.f};
            acc[i][j] = z;
        }

    const int srow = tid >> 2;          // 0..63
    const int sch  = (tid & 3) * 8;
    const bf16* gA = A  + (size_t)(by * 128 + srow) * LDK + sch;
    const bf16* gB = Bp + (size_t)(bxl * 64 + srow) * LDK + sch;
    const size_t A64 = (size_t)64 * LDK;
    bf16* ldsA = As + w * 512;
    bf16* ldsB = Bs + w * 512;

    GEMM_K_LOOP_12864(LDK)

    // epilogue. C/D layout: col = lane&15, row = quad*4 + reg  [m89/m91]
    if (mode == 2) {
        // V: transpose-store vt[d][s], 4 consecutive s packed -> b64
#pragma unroll
        for (int i = 0; i < 2; ++i)
#pragma unroll
            for (int j = 0; j < 4; ++j) {
                const int col = bxl * 64 + j * 16 + l15;                  // d
                const int rowb = by * 128 + w * 32 + i * 16 + quad * 4;   // s base
                bf16 t[4];
#pragma unroll
                for (int r = 0; r < 4; ++r) t[r] = __float2bfloat16(acc[i][j][r]);
                *(short4v*)&vt[(size_t)col * 2048 + rowb] = *(const short4v*)t;
            }
    } else {
        // Q/K: RoPE (head dim 64; tile is head-aligned, d = j*16+l15,
        // partner j^2 in-wave). Q also pre-scaled by 1/8.
        bf16* C = (mode == 0) ? qb : kb;
        const int Nn = (mode == 0) ? 2048 : 512;
        const float scale = (mode == 0) ? 0.125f : 1.0f;
        const float LOG2_1E4 = 13.28771237954945f;
        const float ifr0 = exp2f(-((float)l15) * (LOG2_1E4 / 32.f));
        const float ifr1 = exp2f(-((float)(16 + l15)) * (LOG2_1E4 / 32.f));
#pragma unroll
        for (int i = 0; i < 2; ++i) {
#pragma unroll
            for (int r = 0; r < 4; ++r) {
                const int row = by * 128 + w * 32 + i * 16 + quad * 4 + r;
                float s0, c0, s1, c1;
                sincosf((float)row * ifr0, &s0, &c0);
                sincosf((float)row * ifr1, &s1, &c1);
#pragma unroll
                for (int j = 0; j < 4; ++j) {
                    const float x  = acc[i][j][r];
                    const float xp = acc[i][j ^ 2][r];
                    const float cs = (j & 1) ? c1 : c0;
                    const float sn = (j & 1) ? s1 : s0;
                    const float oo = (x * cs + ((j < 2) ? -xp : xp) * sn) * scale;
                    const int col = bxl * 64 + j * 16 + l15;
                    C[(size_t)row * Nn + col] = __float2bfloat16(oo);
                }
            }
        }
    }
}

// ---------------------------------------------------------------------------
// O-projection, 128x64 tiles: grid (32,16) = 512 blocks. fp32 store.
// ---------------------------------------------------------------------------
__global__ __launch_bounds__(256) void gemm_out(
    const bf16* __restrict__ A, const bf16* __restrict__ B, float* __restrict__ C)
{
    constexpr int LDK = 2048;
    __shared__ bf16 As[2 * 128 * 32];
    __shared__ bf16 Bs[2 * 64 * 32];

    const int tid  = threadIdx.x;
    const int lane = tid & 63;
    const int w    = tid >> 6;
    const int quad = lane >> 4, l15 = lane & 15;
    const int bx = blockIdx.x, by = blockIdx.y;

    floatx4 acc[2][4];
#pragma unroll
    for (int i = 0; i < 2; ++i)
#pragma unroll
        for (int j = 0; j < 4; ++j) {
            floatx4 z = {0.f, 0.f, 0.f, 0.f};
            acc[i][j] = z;
        }

    const int srow = tid >> 2;
    const int sch  = (tid & 3) * 8;
    const bf16* gA = A + (size_t)(by * 128 + srow) * LDK + sch;
    const bf16* gB = B + (size_t)(bx * 64 + srow) * LDK + sch;
    const size_t A64 = (size_t)64 * LDK;
    bf16* ldsA = As + w * 512;
    bf16* ldsB = Bs + w * 512;

    GEMM_K_LOOP_12864(LDK)

#pragma unroll
    for (int i = 0; i < 2; ++i)
#pragma unroll
        for (int j = 0; j < 4; ++j)
#pragma unroll
            for (int r = 0; r < 4; ++r) {
                const int row = by * 128 + w * 32 + i * 16 + quad * 4 + r;
                const int col = bx * 64 + j * 16 + l15;
                C[(size_t)row * 2048 + col] = acc[i][j][r];
            }
}

// ---------------------------------------------------------------------------
// Causal GQA flash attention v7: round-0 fattn4b body (65us known-good,
// LDS-staged K/V, S^T trick, stride-72 dbuf, b64 P-writes), UN-PAIRED
// with a CU-BALANCE-AWARE grid of 1024 blocks.
//
// Round-1 lesson: workgroup->CU assignment ~ id mod 256; gridDim.x=32
// divides 256, so naive unpairing put 4 EQUAL-length blocks on each CU
// (4x32 iters on some CUs, 4x1 on others). Round-2 lesson: direct-from-L2
// fragment reads are TA-bound (16 scattered 64B segments per b128 load);
// LDS staging is what converts coalesced global into scatter-shaped reads.
//
// v7 mapping: j=id&255, s=id>>8; a=(s&1)?31-(j&31):(j&31); h=(s<<3)|(j>>5).
// Bijective onto (h,a); each CU residency class {id = j mod 256} gets
// lengths {a+1, 32-a, a+1, 32-a} = 66 iters total -- the diagonal
// pairing's balance recovered ACROSS resident slots. 45.5KB LDS -> 3
// blocks/CU co-resident (vs 2 with the 512 paired grid); 3x overlap of
// the serial chain saturates the LDS pipe (~1300 cyc/block-iter demand
// vs 2365 measured chain) -> expect ~39-48us.
// ---------------------------------------------------------------------------
__global__ __launch_bounds__(256) void fattn7(
    const bf16* __restrict__ q, const bf16* __restrict__ k,
    const bf16* __restrict__ vt, bf16* __restrict__ o)
{
    __shared__ bf16 Ks[2][64 * 72];
    __shared__ bf16 Vs[2][64 * 72];
    __shared__ bf16 Ps[4][16 * 68];

    const int id = blockIdx.x;
    const int j  = id & 255;
    const int s  = id >> 8;                       // residency slot 0..3
    const int a  = (s & 1) ? (31 - (j & 31)) : (j & 31);
    const int h  = (s << 3) | (j >> 5);
    const int kvh = h >> 2;                       // GQA groups = 4
    const int tid = threadIdx.x, lane = tid & 63, w = tid >> 6;
    const int quad = lane >> 4, l15 = lane & 15;
    bf16* P = Ps[w];

    short ob[8];
#pragma unroll
    for (int e = 0; e < 8; ++e) ob[e] = (short)0x3F80;  // bf16 1.0
    const short8 ones = *(const short8*)ob;

    const int srow = tid >> 3;
    const int ch8  = (tid & 7) * 8;
    const bf16* kg = k  + (size_t)kvh * 64 + ch8;
    const bf16* vg = vt + (size_t)(kvh * 64 + srow) * 2048 + ch8;

    const int qrow0 = a * 64 + w * 16;

    short8 qf[2];
#pragma unroll
    for (int ks = 0; ks < 2; ++ks)
        qf[ks] = *(const short8*)&q[(size_t)(qrow0 + l15) * 2048 + h * 64 + ks * 32 + quad * 8];

    floatx4 o_acc[4], l_acc;
#pragma unroll
    for (int n4 = 0; n4 < 4; ++n4) {
        floatx4 z = {0.f, 0.f, 0.f, 0.f};
        o_acc[n4] = z;
    }
    { floatx4 z = {0.f, 0.f, 0.f, 0.f}; l_acc = z; }

    {
        short8 k0 = *(const short8*)(kg + (size_t)srow * 512);
        short8 k1 = *(const short8*)(kg + (size_t)(srow + 32) * 512);
        short8 v0 = *(const short8*)(vg);
        short8 v1 = *(const short8*)(vg + (size_t)32 * 2048);
        *(short8*)&Ks[0][srow * 72 + ch8]        = k0;
        *(short8*)&Ks[0][(srow + 32) * 72 + ch8] = k1;
        *(short8*)&Vs[0][srow * 72 + ch8]        = v0;
        *(short8*)&Vs[0][(srow + 32) * 72 + ch8] = v1;
    }
    __syncthreads();

    for (int kt = 0; kt <= a; ++kt) {
        const int buf = kt & 1;

        short8 nk0, nk1, nv0, nv1;
        if (kt < a) {
            const size_t kr = (size_t)((kt + 1) * 64) * 512;
            nk0 = *(const short8*)(kg + kr + (size_t)srow * 512);
            nk1 = *(const short8*)(kg + kr + (size_t)(srow + 32) * 512);
            nv0 = *(const short8*)(vg + (kt + 1) * 64);
            nv1 = *(const short8*)(vg + (size_t)32 * 2048 + (kt + 1) * 64);
        }

        // S^T = K Q^T: A=kf (m=skey), B=qf (n=qrow).
        // C: col=l15 -> qrow, row=quad*4+r -> skey = n*16+quad*4+r.
        floatx4 s_acc[4];
#pragma unroll
        for (int n = 0; n < 4; ++n) {
            floatx4 z = {0.f, 0.f, 0.f, 0.f};
            s_acc[n] = z;
        }
        __builtin_amdgcn_s_setprio(1);
#pragma unroll
        for (int n = 0; n < 4; ++n)
#pragma unroll
            for (int ks = 0; ks < 2; ++ks) {
                const short8 kf = *(const short8*)&Ks[buf][(n * 16 + l15) * 72 + ks * 32 + quad * 8];
                s_acc[n] = MFMA16(kf, qf[ks], s_acc[n]);
            }
        __builtin_amdgcn_s_setprio(0);

        // exp -> P[qrow][skey], 4 consecutive skeys per lane -> b64 write
        if (kt < a) {
#pragma unroll
            for (int n = 0; n < 4; ++n) {
                bf16 t4[4];
#pragma unroll
                for (int r = 0; r < 4; ++r)
                    t4[r] = __float2bfloat16(__expf(s_acc[n][r]));
                *(short4v*)&P[l15 * 68 + n * 16 + quad * 4] = *(const short4v*)t4;
            }
        } else {
            // diagonal: allow skey <= qrow (within 64-row block)
#pragma unroll
            for (int n = 0; n < 4; ++n) {
                bf16 t4[4];
#pragma unroll
                for (int r = 0; r < 4; ++r) {
                    const bool okc = (n * 16 + quad * 4 + r) <= (w * 16 + l15);
                    t4[r] = __float2bfloat16(okc ? __expf(s_acc[n][r]) : 0.f);
                }
                *(short4v*)&P[l15 * 68 + n * 16 + quad * 4] = *(const short4v*)t4;
            }
        }

        __builtin_amdgcn_s_setprio(1);
#pragma unroll
        for (int ks2 = 0; ks2 < 2; ++ks2) {
            const short8 pf = *(const short8*)&P[l15 * 68 + ks2 * 32 + quad * 8];
            l_acc = MFMA16(pf, ones, l_acc);
#pragma unroll
            for (int n4 = 0; n4 < 4; ++n4) {
                const short8 vf = *(const short8*)&Vs[buf][(n4 * 16 + l15) * 72 + ks2 * 32 + quad * 8];
                o_acc[n4] = MFMA16(pf, vf, o_acc[n4]);
            }
        }
        __builtin_amdgcn_s_setprio(0);

        if (kt < a) {
            *(short8*)&Ks[buf ^ 1][srow * 72 + ch8]        = nk0;
            *(short8*)&Ks[buf ^ 1][(srow + 32) * 72 + ch8] = nk1;
            *(short8*)&Vs[buf ^ 1][srow * 72 + ch8]        = nv0;
            *(short8*)&Vs[buf ^ 1][(srow + 32) * 72 + ch8] = nv1;
        }
        __syncthreads();
    }

#pragma unroll
    for (int n4 = 0; n4 < 4; ++n4)
#pragma unroll
        for (int r = 0; r < 4; ++r) {
            const float val = o_acc[n4][r] / l_acc[r];
            const int row = qrow0 + quad * 4 + r;
            const int col = h * 64 + n4 * 16 + l15;
            o[(size_t)row * 2048 + col] = __float2bfloat16(val);
        }
}

// ---------------------------------------------------------------------------
extern "C" void kernel_launch(void* const* d_in, const int* in_sizes, int n_in,
                              void* d_out, int out_size, void* d_ws, size_t ws_size,
                              hipStream_t stream)
{
    const float* hs = (const float*)d_in[0];
    const float* Wq = (const float*)d_in[1];
    const float* Wk = (const float*)d_in[2];
    const float* Wv = (const float*)d_in[3];
    const float* Wo = (const float*)d_in[4];
    float* out = (float*)d_out;

    bf16* ws  = (bf16*)d_ws;
    bf16* hsb = ws;                  // 4,194,304
    bf16* Wqb = ws + 4194304;        // 4,194,304
    bf16* Wkb = ws + 8388608;        // 1,048,576
    bf16* Wvb = ws + 9437184;        // 1,048,576
    bf16* Wob = ws + 10485760;       // 4,194,304
    bf16* qb  = ws + 14680064;       // 4,194,304  (RoPE'd, 1/8-scaled)
    bf16* kb  = ws + 18874368;       // 1,048,576  (RoPE'd)
    bf16* vtb = ws + 19922944;       // 1,048,576  (V^T [512][2048])
    bf16* ab  = ws + 20971520;       // 4,194,304  (attention out)

    dim3 blk(256);
    cvt_all<<<7168, blk, 0, stream>>>(hs, Wq, Wk, Wv, Wo, hsb, Wqb, Wkb, Wvb, Wob);
    gemm_qkv<<<dim3(48, 16), blk, 0, stream>>>(hsb, Wqb, Wkb, Wvb, qb, kb, vtb);
    fattn7<<<dim3(1024), blk, 0, stream>>>(qb, kb, vtb, ab);
    gemm_out<<<dim3(32, 16), blk, 0, stream>>>(ab, Wob, out);
}

// Round 4
// 219.571 us; speedup vs baseline: 1.3227x; 1.0932x over previous
//
#include <hip/hip_runtime.h>
#include <hip/hip_bf16.h>
#include <math.h>

typedef __hip_bfloat16 bf16;
typedef __attribute__((ext_vector_type(8))) short short8;
typedef __attribute__((ext_vector_type(4))) short short4v;
typedef __attribute__((ext_vector_type(4))) float floatx4;

#define MFMA16(a, b, c) __builtin_amdgcn_mfma_f32_16x16x32_bf16((a), (b), (c), 0, 0, 0)

typedef const __attribute__((address_space(1))) void* as1_cvp;
typedef __attribute__((address_space(3))) void* as3_vp;

__device__ __forceinline__ void gload_lds16(const bf16* g, bf16* lds_uni) {
    __builtin_amdgcn_global_load_lds((as1_cvp)g, (as3_vp)lds_uni, 16, 0, 0);
}

// ---------------------------------------------------------------------------
// Single-launch fp32 -> bf16 convert of all 5 inputs (segmented grid).
// ---------------------------------------------------------------------------
__global__ __launch_bounds__(256) void cvt_all(
    const float* __restrict__ a0, const float* __restrict__ a1,
    const float* __restrict__ a2, const float* __restrict__ a3,
    const float* __restrict__ a4,
    bf16* __restrict__ d0, bf16* __restrict__ d1, bf16* __restrict__ d2,
    bf16* __restrict__ d3, bf16* __restrict__ d4)
{
    const int b = blockIdx.x;
    const float* src; bf16* dst; int off;
    if (b < 2048)      { src = a0; dst = d0; off = b; }
    else if (b < 4096) { src = a1; dst = d1; off = b - 2048; }
    else if (b < 4608) { src = a2; dst = d2; off = b - 4096; }
    else if (b < 5120) { src = a3; dst = d3; off = b - 4608; }
    else               { src = a4; dst = d4; off = b - 5120; }
    const int i = (off * 256 + threadIdx.x) * 8;
    const float4 x = *(const float4*)(src + i);
    const float4 y = *(const float4*)(src + i + 4);
    bf16 t[8];
    t[0] = __float2bfloat16(x.x); t[1] = __float2bfloat16(x.y);
    t[2] = __float2bfloat16(x.z); t[3] = __float2bfloat16(x.w);
    t[4] = __float2bfloat16(y.x); t[5] = __float2bfloat16(y.y);
    t[6] = __float2bfloat16(y.z); t[7] = __float2bfloat16(y.w);
    *(short8*)(dst + i) = *(const short8*)t;
}

// ---------------------------------------------------------------------------
// 128x64-tile GEMM K-loop, DOUBLE-BUFFERED with counted vmcnt (T4).
//
// Round-4 change: the old loop did {issue 6 gload_lds -> __syncthreads
// (drains vmcnt(0): full VMEM latency exposed every K-step) -> compute ->
// barrier}. New loop: LDS dbuf (24->48KB, still 3 blocks/CU), issue the
// NEXT tile's 6 loads first, then s_waitcnt vmcnt(6) (current tile's
// loads done, next tile's 6 stay in flight across the barrier) + raw
// s_barrier. Never vmcnt(0) in the main loop. Second barrier after
// compute protects buf from next iteration's overwrite (reads are
// consumed before it via compiler lgkmcnt waits).
// ---------------------------------------------------------------------------
#define GEMM_STAGE6(k0, sA, sB)                                                 \
    gload_lds16(gA + (k0),            (sA));                                    \
    gload_lds16(gA + A64 + (k0),      (sA) + 2048);                             \
    gload_lds16(gB + (k0),            (sB));                                    \
    gload_lds16(gA + (k0) + 32,       (sA) + 4096);                             \
    gload_lds16(gA + A64 + (k0) + 32, (sA) + 6144);                             \
    gload_lds16(gB + (k0) + 32,       (sB) + 2048);

#define GEMM_K_LOOP_DB(KB)                                                      \
    {                                                                           \
        bf16* sA0 = &As[0][0] + w * 512; bf16* sB0 = &Bs[0][0] + w * 512;       \
        bf16* sA1 = &As[1][0] + w * 512; bf16* sB1 = &Bs[1][0] + w * 512;       \
        GEMM_STAGE6(0, sA0, sB0)                                                \
        for (int k0 = 0; k0 < (KB); k0 += 64) {                                 \
            const int cur = (k0 >> 6) & 1;                                      \
            if (k0 + 64 < (KB)) {                                               \
                if (cur == 0) { GEMM_STAGE6(k0 + 64, sA1, sB1) }                \
                else          { GEMM_STAGE6(k0 + 64, sA0, sB0) }                \
                asm volatile("s_waitcnt vmcnt(6)" ::: "memory");                \
            } else {                                                            \
                asm volatile("s_waitcnt vmcnt(0)" ::: "memory");                \
            }                                                                   \
            __builtin_amdgcn_s_barrier();                                       \
            const bf16* Acur = &As[cur][0];                                     \
            const bf16* Bcur = &Bs[cur][0];                                     \
            _Pragma("unroll")                                                   \
            for (int hh = 0; hh < 2; ++hh) {                                    \
                short8 af[2], bfr[4];                                           \
                _Pragma("unroll")                                               \
                for (int i = 0; i < 2; ++i)                                     \
                    af[i] = *(const short8*)&Acur[hh * 4096 + (w * 32 + i * 16 + l15) * 32 + quad * 8]; \
                _Pragma("unroll")                                               \
                for (int j = 0; j < 4; ++j)                                     \
                    bfr[j] = *(const short8*)&Bcur[hh * 2048 + (j * 16 + l15) * 32 + quad * 8]; \
                _Pragma("unroll")                                               \
                for (int i = 0; i < 2; ++i)                                     \
                    _Pragma("unroll")                                           \
                    for (int j = 0; j < 4; ++j)                                 \
                        acc[i][j] = MFMA16(af[i], bfr[j], acc[i][j]);           \
            }                                                                   \
            __builtin_amdgcn_s_barrier();                                       \
        }                                                                       \
    }

// ---------------------------------------------------------------------------
// Fused QKV projection, 128x64 tiles. grid (48,16):
//   bx  0..31: Q (RoPE + 1/8 scale -> qb)
//   bx 32..39: K (RoPE -> kb)
//   bx 40..47: V (transpose-store -> vt[512][2048])
// ---------------------------------------------------------------------------
__global__ __launch_bounds__(256) void gemm_qkv(
    const bf16* __restrict__ A, const bf16* __restrict__ Wq,
    const bf16* __restrict__ Wk, const bf16* __restrict__ Wv,
    bf16* __restrict__ qb, bf16* __restrict__ kb, bf16* __restrict__ vt)
{
    constexpr int LDK = 2048;
    __shared__ bf16 As[2][128 * 64];    // 32 KB (dbuf)
    __shared__ bf16 Bs[2][64 * 64];     // 16 KB (dbuf)

    const int tid  = threadIdx.x;
    const int lane = tid & 63;
    const int w    = tid >> 6;
    const int quad = lane >> 4, l15 = lane & 15;
    const int bx = blockIdx.x, by = blockIdx.y;

    const bf16* Bp; int bxl, mode;
    if (bx < 32)      { Bp = Wq; bxl = bx;      mode = 0; }
    else if (bx < 40) { Bp = Wk; bxl = bx - 32; mode = 1; }
    else              { Bp = Wv; bxl = bx - 40; mode = 2; }

    floatx4 acc[2][4];
#pragma unroll
    for (int i = 0; i < 2; ++i)
#pragma unroll
        for (int j = 0; j < 4; ++j) {
            floatx4 z = {0.f, 0.f, 0.f, 0.f};
            acc[i][j] = z;
        }

    const int srow = tid >> 2;          // 0..63
    const int sch  = (tid & 3) * 8;
    const bf16* gA = A  + (size_t)(by * 128 + srow) * LDK + sch;
    const bf16* gB = Bp + (size_t)(bxl * 64 + srow) * LDK + sch;
    const size_t A64 = (size_t)64 * LDK;

    GEMM_K_LOOP_DB(LDK)

    // epilogue. C/D layout: col = lane&15, row = quad*4 + reg  [m89/m91]
    if (mode == 2) {
        // V: transpose-store vt[d][s], 4 consecutive s packed -> b64
#pragma unroll
        for (int i = 0; i < 2; ++i)
#pragma unroll
            for (int j = 0; j < 4; ++j) {
                const int col = bxl * 64 + j * 16 + l15;                  // d
                const int rowb = by * 128 + w * 32 + i * 16 + quad * 4;   // s base
                bf16 t[4];
#pragma unroll
                for (int r = 0; r < 4; ++r) t[r] = __float2bfloat16(acc[i][j][r]);
                *(short4v*)&vt[(size_t)col * 2048 + rowb] = *(const short4v*)t;
            }
    } else {
        // Q/K: RoPE (head dim 64; tile is head-aligned, d = j*16+l15,
        // partner j^2 in-wave). Q also pre-scaled by 1/8.
        bf16* C = (mode == 0) ? qb : kb;
        const int Nn = (mode == 0) ? 2048 : 512;
        const float scale = (mode == 0) ? 0.125f : 1.0f;
        const float LOG2_1E4 = 13.28771237954945f;
        const float ifr0 = exp2f(-((float)l15) * (LOG2_1E4 / 32.f));
        const float ifr1 = exp2f(-((float)(16 + l15)) * (LOG2_1E4 / 32.f));
#pragma unroll
        for (int i = 0; i < 2; ++i) {
#pragma unroll
            for (int r = 0; r < 4; ++r) {
                const int row = by * 128 + w * 32 + i * 16 + quad * 4 + r;
                float s0, c0, s1, c1;
                sincosf((float)row * ifr0, &s0, &c0);
                sincosf((float)row * ifr1, &s1, &c1);
#pragma unroll
                for (int j = 0; j < 4; ++j) {
                    const float x  = acc[i][j][r];
                    const float xp = acc[i][j ^ 2][r];
                    const float cs = (j & 1) ? c1 : c0;
                    const float sn = (j & 1) ? s1 : s0;
                    const float oo = (x * cs + ((j < 2) ? -xp : xp) * sn) * scale;
                    const int col = bxl * 64 + j * 16 + l15;
                    C[(size_t)row * Nn + col] = __float2bfloat16(oo);
                }
            }
        }
    }
}

// ---------------------------------------------------------------------------
// O-projection, 128x64 tiles: grid (32,16) = 512 blocks. fp32 store.
// ---------------------------------------------------------------------------
__global__ __launch_bounds__(256) void gemm_out(
    const bf16* __restrict__ A, const bf16* __restrict__ B, float* __restrict__ C)
{
    constexpr int LDK = 2048;
    __shared__ bf16 As[2][128 * 64];
    __shared__ bf16 Bs[2][64 * 64];

    const int tid  = threadIdx.x;
    const int lane = tid & 63;
    const int w    = tid >> 6;
    const int quad = lane >> 4, l15 = lane & 15;
    const int bx = blockIdx.x, by = blockIdx.y;

    floatx4 acc[2][4];
#pragma unroll
    for (int i = 0; i < 2; ++i)
#pragma unroll
        for (int j = 0; j < 4; ++j) {
            floatx4 z = {0.f, 0.f, 0.f, 0.f};
            acc[i][j] = z;
        }

    const int srow = tid >> 2;
    const int sch  = (tid & 3) * 8;
    const bf16* gA = A + (size_t)(by * 128 + srow) * LDK + sch;
    const bf16* gB = B + (size_t)(bx * 64 + srow) * LDK + sch;
    const size_t A64 = (size_t)64 * LDK;

    GEMM_K_LOOP_DB(LDK)

#pragma unroll
    for (int i = 0; i < 2; ++i)
#pragma unroll
        for (int j = 0; j < 4; ++j)
#pragma unroll
            for (int r = 0; r < 4; ++r) {
                const int row = by * 128 + w * 32 + i * 16 + quad * 4 + r;
                const int col = bx * 64 + j * 16 + l15;
                C[(size_t)row * 2048 + col] = acc[i][j][r];
            }
}

// ---------------------------------------------------------------------------
// Causal GQA flash attention: EXACT round-0 fattn4b (65us measured).
// S^T trick (S^T = MFMA(K,Q): lane holds 4 consecutive skeys per qrow ->
// P written as 4x b64), diagonal pairing (tile t + 31-t = uniform 33
// iters, which is ALSO the CU load balancer -- rounds 1/3 proved
// unpaired variants regress), stride-72 dbuf staging, ones-MFMA row-sum.
// Occupancy-raising attempts (1024 blocks, balanced mappings, setprio)
// all measured negative; this config is the grid-axis local optimum.
// ---------------------------------------------------------------------------
__global__ __launch_bounds__(256) void fattn4b(
    const bf16* __restrict__ q, const bf16* __restrict__ k,
    const bf16* __restrict__ vt, bf16* __restrict__ o)
{
    __shared__ bf16 Ks[2][64 * 72];
    __shared__ bf16 Vs[2][64 * 72];
    __shared__ bf16 Ps[4][16 * 68];

    const int tpair = blockIdx.x;
    const int h = blockIdx.y;
    const int kvh = h >> 2;             // GQA groups = 4
    const int tid = threadIdx.x, lane = tid & 63, w = tid >> 6;
    const int quad = lane >> 4, l15 = lane & 15;
    bf16* P = Ps[w];

    short ob[8];
#pragma unroll
    for (int e = 0; e < 8; ++e) ob[e] = (short)0x3F80;  // bf16 1.0
    const short8 ones = *(const short8*)ob;

    const int srow = tid >> 3;
    const int ch8  = (tid & 7) * 8;
    const bf16* kg = k  + (size_t)kvh * 64 + ch8;
    const bf16* vg = vt + (size_t)(kvh * 64 + srow) * 2048 + ch8;

#pragma unroll 1
    for (int ph = 0; ph < 2; ++ph) {
        const int a = ph ? (31 - tpair) : tpair;
        const int qrow0 = a * 64 + w * 16;

        short8 qf[2];
#pragma unroll
        for (int ks = 0; ks < 2; ++ks)
            qf[ks] = *(const short8*)&q[(size_t)(qrow0 + l15) * 2048 + h * 64 + ks * 32 + quad * 8];

        floatx4 o_acc[4], l_acc;
#pragma unroll
        for (int n4 = 0; n4 < 4; ++n4) {
            floatx4 z = {0.f, 0.f, 0.f, 0.f};
            o_acc[n4] = z;
        }
        { floatx4 z = {0.f, 0.f, 0.f, 0.f}; l_acc = z; }

        {
            short8 k0 = *(const short8*)(kg + (size_t)srow * 512);
            short8 k1 = *(const short8*)(kg + (size_t)(srow + 32) * 512);
            short8 v0 = *(const short8*)(vg);
            short8 v1 = *(const short8*)(vg + (size_t)32 * 2048);
            *(short8*)&Ks[0][srow * 72 + ch8]        = k0;
            *(short8*)&Ks[0][(srow + 32) * 72 + ch8] = k1;
            *(short8*)&Vs[0][srow * 72 + ch8]        = v0;
            *(short8*)&Vs[0][(srow + 32) * 72 + ch8] = v1;
        }
        __syncthreads();

        for (int kt = 0; kt <= a; ++kt) {
            const int buf = kt & 1;

            short8 nk0, nk1, nv0, nv1;
            if (kt < a) {
                const size_t kr = (size_t)((kt + 1) * 64) * 512;
                nk0 = *(const short8*)(kg + kr + (size_t)srow * 512);
                nk1 = *(const short8*)(kg + kr + (size_t)(srow + 32) * 512);
                nv0 = *(const short8*)(vg + (kt + 1) * 64);
                nv1 = *(const short8*)(vg + (size_t)32 * 2048 + (kt + 1) * 64);
            }

            // S^T = K Q^T: A=kf (m=skey), B=qf (n=qrow).
            // C: col=l15 -> qrow, row=quad*4+r -> skey = n*16+quad*4+r.
            floatx4 s_acc[4];
#pragma unroll
            for (int n = 0; n < 4; ++n) {
                floatx4 z = {0.f, 0.f, 0.f, 0.f};
                s_acc[n] = z;
            }
#pragma unroll
            for (int n = 0; n < 4; ++n)
#pragma unroll
                for (int ks = 0; ks < 2; ++ks) {
                    const short8 kf = *(const short8*)&Ks[buf][(n * 16 + l15) * 72 + ks * 32 + quad * 8];
                    s_acc[n] = MFMA16(kf, qf[ks], s_acc[n]);
                }

            // exp -> P[qrow][skey], 4 consecutive skeys per lane -> b64 write
            if (kt < a) {
#pragma unroll
                for (int n = 0; n < 4; ++n) {
                    bf16 t4[4];
#pragma unroll
                    for (int r = 0; r < 4; ++r)
                        t4[r] = __float2bfloat16(__expf(s_acc[n][r]));
                    *(short4v*)&P[l15 * 68 + n * 16 + quad * 4] = *(const short4v*)t4;
                }
            } else {
                // diagonal: allow skey <= qrow (within 64-row block)
#pragma unroll
                for (int n = 0; n < 4; ++n) {
                    bf16 t4[4];
#pragma unroll
                    for (int r = 0; r < 4; ++r) {
                        const bool okc = (n * 16 + quad * 4 + r) <= (w * 16 + l15);
                        t4[r] = __float2bfloat16(okc ? __expf(s_acc[n][r]) : 0.f);
                    }
                    *(short4v*)&P[l15 * 68 + n * 16 + quad * 4] = *(const short4v*)t4;
                }
            }

#pragma unroll
            for (int ks2 = 0; ks2 < 2; ++ks2) {
                const short8 pf = *(const short8*)&P[l15 * 68 + ks2 * 32 + quad * 8];
                l_acc = MFMA16(pf, ones, l_acc);
#pragma unroll
                for (int n4 = 0; n4 < 4; ++n4) {
                    const short8 vf = *(const short8*)&Vs[buf][(n4 * 16 + l15) * 72 + ks2 * 32 + quad * 8];
                    o_acc[n4] = MFMA16(pf, vf, o_acc[n4]);
                }
            }

            if (kt < a) {
                *(short8*)&Ks[buf ^ 1][srow * 72 + ch8]        = nk0;
                *(short8*)&Ks[buf ^ 1][(srow + 32) * 72 + ch8] = nk1;
                *(short8*)&Vs[buf ^ 1][srow * 72 + ch8]        = nv0;
                *(short8*)&Vs[buf ^ 1][(srow + 32) * 72 + ch8] = nv1;
            }
            __syncthreads();
        }

#pragma unroll
        for (int n4 = 0; n4 < 4; ++n4)
#pragma unroll
            for (int r = 0; r < 4; ++r) {
                const float val = o_acc[n4][r] / l_acc[r];
                const int row = qrow0 + quad * 4 + r;
                const int col = h * 64 + n4 * 16 + l15;
                o[(size_t)row * 2048 + col] = __float2bfloat16(val);
            }
    }
}

// ---------------------------------------------------------------------------
extern "C" void kernel_launch(void* const* d_in, const int* in_sizes, int n_in,
                              void* d_out, int out_size, void* d_ws, size_t ws_size,
                              hipStream_t stream)
{
    const float* hs = (const float*)d_in[0];
    const float* Wq = (const float*)d_in[1];
    const float* Wk = (const float*)d_in[2];
    const float* Wv = (const float*)d_in[3];
    const float* Wo = (const float*)d_in[4];
    float* out = (float*)d_out;

    bf16* ws  = (bf16*)d_ws;
    bf16* hsb = ws;                  // 4,194,304
    bf16* Wqb = ws + 4194304;        // 4,194,304
    bf16* Wkb = ws + 8388608;        // 1,048,576
    bf16* Wvb = ws + 9437184;        // 1,048,576
    bf16* Wob = ws + 10485760;       // 4,194,304
    bf16* qb  = ws + 14680064;       // 4,194,304  (RoPE'd, 1/8-scaled)
    bf16* kb  = ws + 18874368;       // 1,048,576  (RoPE'd)
    bf16* vtb = ws + 19922944;       // 1,048,576  (V^T [512][2048])
    bf16* ab  = ws + 20971520;       // 4,194,304  (attention out)

    dim3 blk(256);
    cvt_all<<<7168, blk, 0, stream>>>(hs, Wq, Wk, Wv, Wo, hsb, Wqb, Wkb, Wvb, Wob);
    gemm_qkv<<<dim3(48, 16), blk, 0, stream>>>(hsb, Wqb, Wkb, Wvb, qb, kb, vtb);
    fattn4b<<<dim3(16, 32), blk, 0, stream>>>(qb, kb, vtb, ab);
    gemm_out<<<dim3(32, 16), blk, 0, stream>>>(ab, Wob, out);
}